// Round 2
// baseline (32.976 us; speedup 1.0000x reference)
//
#include <hip/hip_runtime.h>

// out[0] = mean(|pred - mask|) over 16Mi fp32 elements (conv loop in the
// reference is dead code). Memory-bound streaming reduction.
//
// Round-2 change: the grid-stride loop (VGPR=8, ~2 loads in flight) was
// latency-bound at 3.3 TB/s effective. Problem size divides exactly:
// 4,194,304 float4 = 2048 blocks x 256 threads x 8 per thread. Fully unroll
// and stage all 16 float4 loads (8 pred + 8 mask) in registers before
// computing -> 256 B/lane in flight, maximum MLP.

#define NTHREADS 256
#define NBLOCKS  2048
#define PER_THREAD 8
#define STRIDE (NBLOCKS * NTHREADS)  // 524,288 threads; x8 = 4,194,304 float4

__global__ __launch_bounds__(NTHREADS) void abs_diff_partial(
    const float4* __restrict__ pred,
    const float4* __restrict__ mask,
    float* __restrict__ partial) {
    const unsigned tid = blockIdx.x * NTHREADS + threadIdx.x;

    float4 p[PER_THREAD], m[PER_THREAD];
    #pragma unroll
    for (int k = 0; k < PER_THREAD; ++k) p[k] = pred[tid + k * STRIDE];
    #pragma unroll
    for (int k = 0; k < PER_THREAD; ++k) m[k] = mask[tid + k * STRIDE];

    // 4 independent accumulator chains (VALU is nearly idle anyway)
    float a0 = 0.f, a1 = 0.f, a2 = 0.f, a3 = 0.f;
    #pragma unroll
    for (int k = 0; k < PER_THREAD; ++k) {
        a0 += fabsf(p[k].x - m[k].x);
        a1 += fabsf(p[k].y - m[k].y);
        a2 += fabsf(p[k].z - m[k].z);
        a3 += fabsf(p[k].w - m[k].w);
    }
    float acc = (a0 + a1) + (a2 + a3);

    // wave-64 shuffle reduce
    #pragma unroll
    for (int off = 32; off > 0; off >>= 1)
        acc += __shfl_down(acc, off, 64);

    __shared__ float s[NTHREADS / 64];
    const int lane = threadIdx.x & 63;
    const int wid  = threadIdx.x >> 6;
    if (lane == 0) s[wid] = acc;
    __syncthreads();
    if (threadIdx.x == 0) {
        partial[blockIdx.x] = (s[0] + s[1]) + (s[2] + s[3]);  // fixed order
    }
}

__global__ __launch_bounds__(NTHREADS) void final_reduce(
    const float* __restrict__ partial, float* __restrict__ out) {
    float acc = 0.0f;
    for (int i = threadIdx.x; i < NBLOCKS; i += NTHREADS)
        acc += partial[i];
    #pragma unroll
    for (int off = 32; off > 0; off >>= 1)
        acc += __shfl_down(acc, off, 64);

    __shared__ float s[NTHREADS / 64];
    const int lane = threadIdx.x & 63;
    const int wid  = threadIdx.x >> 6;
    if (lane == 0) s[wid] = acc;
    __syncthreads();
    if (threadIdx.x == 0) {
        float b = (s[0] + s[1]) + (s[2] + s[3]);
        out[0] = b / (float)(16u * 1024u * 1024u);
    }
}

extern "C" void kernel_launch(void* const* d_in, const int* in_sizes, int n_in,
                              void* d_out, int out_size, void* d_ws, size_t ws_size,
                              hipStream_t stream) {
    const float4* pred = (const float4*)d_in[0];
    const float4* mask = (const float4*)d_in[1];
    float* out = (float*)d_out;
    float* partial = (float*)d_ws;  // NBLOCKS floats = 8 KB scratch

    abs_diff_partial<<<NBLOCKS, NTHREADS, 0, stream>>>(pred, mask, partial);
    final_reduce<<<1, NTHREADS, 0, stream>>>(partial, out);
}